// Round 6
// baseline (534.924 us; speedup 1.0000x reference)
//
#include <hip/hip_runtime.h>
#include <math.h>

#define NIN 128
#define NOUT 64
#define FEAT 256        // 4 heads * 64, bf16 row for QL
#define KHROW 512       // K(256) | H(256) interleaved bf16 row

typedef __attribute__((ext_vector_type(8))) short short8;
typedef __attribute__((ext_vector_type(4))) float f32x4;

__device__ __forceinline__ unsigned short f2bf(float f) {
    unsigned u = __float_as_uint(f);
    u = (u + 0x7FFFu + ((u >> 16) & 1u)) >> 16;   // RTNE
    return (unsigned short)u;
}
__device__ __forceinline__ float bflo(unsigned u) {
    return __uint_as_float(u << 16);
}
__device__ __forceinline__ float bfhi(unsigned u) {
    return __uint_as_float(u & 0xffff0000u);
}

// ---------------- W fp32 -> bf16, pre-swizzled to MFMA A-fragment order ------
// Wsw[(mat*4+head)*4+tile][kb][lane][8]: element = W[mat][head][tile*16+(lane&15)]
//                                                 [kb*32+(lane>>4)*8 + j]
__global__ __launch_bounds__(256) void wconv_kernel(
    const float* __restrict__ Wq, const float* __restrict__ Wk,
    const float* __restrict__ Wh, unsigned short* __restrict__ Wsw)
{
    const int id = blockIdx.x * 256 + threadIdx.x;   // 12288 total
    const int lane = id & 63;
    const int kb   = (id >> 6) & 3;
    const int tile = (id >> 8) & 3;
    const int head = (id >> 10) & 3;
    const int mat  = id >> 12;
    const float* src = (mat == 0) ? Wq : (mat == 1) ? Wk : Wh;
    const int row   = tile * 16 + (lane & 15);
    const int kbase = kb * 32 + (lane >> 4) * 8;
    const float* sp = src + (size_t)(head * 64 + row) * NIN + kbase;
    const float4 a = *(const float4*)sp;
    const float4 b = *(const float4*)(sp + 4);
    uint4 w;
    w.x = (unsigned)f2bf(a.x) | ((unsigned)f2bf(a.y) << 16);
    w.y = (unsigned)f2bf(a.z) | ((unsigned)f2bf(a.w) << 16);
    w.z = (unsigned)f2bf(b.x) | ((unsigned)f2bf(b.y) << 16);
    w.w = (unsigned)f2bf(b.z) | ((unsigned)f2bf(b.w) << 16);
    *(uint4*)(Wsw + (size_t)id * 8) = w;
}

// ---------------- MFMA GEMM: A=W, B=x  => D[feature][node] -------------------
// Lane's 4 acc regs = 4 consecutive features of ONE node -> direct 8B stores,
// no LDS bounce. feats = tile*16 + (l>>4)*4 + i, node = nb + w*16 + (l&15).
__global__ __launch_bounds__(256) void gemm_mfma_kernel(
    const float* __restrict__ x, const unsigned short* __restrict__ Wsw,
    const float* __restrict__ bh,
    unsigned short* __restrict__ QL, unsigned short* __restrict__ KH, int N)
{
    __shared__ unsigned short xs[64][136];

    const int nb = blockIdx.x * 64;
    const int t  = threadIdx.x;
    const int w  = t >> 6;
    const int l  = t & 63;

    #pragma unroll
    for (int j = 0; j < 8; ++j) {
        const int idx = j * 256 + t;
        const int row = idx >> 5;
        const int c4  = idx & 31;
        float4 xv = make_float4(0.f, 0.f, 0.f, 0.f);
        if (nb + row < N)
            xv = *(const float4*)(x + (size_t)(nb + row) * NIN + c4 * 4);
        ushort4 pk;
        pk.x = f2bf(xv.x); pk.y = f2bf(xv.y); pk.z = f2bf(xv.z); pk.w = f2bf(xv.w);
        *(ushort4*)(&xs[row][c4 * 4]) = pk;
    }
    __syncthreads();

    // B-fragment (x): col(node)=l&15, k=(l>>4)*8+j  — per wave's 16 nodes
    short8 bfrx[4];
    #pragma unroll
    for (int kb = 0; kb < 4; ++kb)
        bfrx[kb] = *(const short8*)(&xs[w * 16 + (l & 15)][kb * 32 + (l >> 4) * 8]);

    const int node = nb + w * 16 + (l & 15);
    const int fsub = (l >> 4) * 4;            // feature sub-offset within tile

    for (int g = 0; g < 12; ++g) {
        const int mat  = g >> 2;
        const int head = g & 3;

        f32x4 acc[4];
        #pragma unroll
        for (int tile = 0; tile < 4; ++tile) {
            acc[tile] = (f32x4){0.f, 0.f, 0.f, 0.f};
            #pragma unroll
            for (int kb = 0; kb < 4; ++kb) {
                // A-fragment (W): row(feature)=l&15 within tile, coalesced 1KB
                const short8 afrw = *(const short8*)(
                    Wsw + ((size_t)((g * 4 + tile) * 4 + kb) << 9) + (l << 3));
                acc[tile] = __builtin_amdgcn_mfma_f32_16x16x32_bf16(
                    afrw, bfrx[kb], acc[tile], 0, 0, 0);
            }
        }

        if (node < N) {
            unsigned short* ob;
            if (mat == 0) ob = QL + (size_t)node * FEAT + head * NOUT;
            else          ob = KH + (size_t)node * KHROW + (mat == 2 ? 256 : 0)
                                  + head * NOUT;
            #pragma unroll
            for (int tile = 0; tile < 4; ++tile) {
                float v0 = acc[tile][0], v1 = acc[tile][1];
                float v2 = acc[tile][2], v3 = acc[tile][3];
                if (mat == 2) {
                    const float* bp = bh + head * NOUT + tile * 16 + fsub;
                    v0 += bp[0]; v1 += bp[1]; v2 += bp[2]; v3 += bp[3];
                } else {
                    v0 = (v0 > 0.f) ? v0 : 0.2f * v0;
                    v1 = (v1 > 0.f) ? v1 : 0.2f * v1;
                    v2 = (v2 > 0.f) ? v2 : 0.2f * v2;
                    v3 = (v3 > 0.f) ? v3 : 0.2f * v3;
                }
                uint2 pk;
                pk.x = (unsigned)f2bf(v0) | ((unsigned)f2bf(v1) << 16);
                pk.y = (unsigned)f2bf(v2) | ((unsigned)f2bf(v3) << 16);
                *(uint2*)(ob + tile * 16 + fsub) = pk;
            }
        }
    }
}

// ---------------- degree count ----------------
__global__ __launch_bounds__(256) void deg_kernel(const int* __restrict__ ei, int E,
                                                  int* __restrict__ deg)
{
    const int e = blockIdx.x * 256 + threadIdx.x;
    if (e < E) atomicAdd(&deg[ei[e]], 1);
}

// ---------------- multi-block scan ----------------
__global__ __launch_bounds__(1024) void bsum_kernel(const int* __restrict__ deg, int N,
                                                    int* __restrict__ bsum)
{
    __shared__ int wsum[16];
    const int t = threadIdx.x;
    const int idx = blockIdx.x * 1024 + t;
    int v = (idx < N) ? deg[idx] : 0;
    #pragma unroll
    for (int off = 1; off < 64; off <<= 1) v += __shfl_xor(v, off);
    if ((t & 63) == 0) wsum[t >> 6] = v;
    __syncthreads();
    if (t < 16) {
        int s = wsum[t];
        #pragma unroll
        for (int off = 1; off < 16; off <<= 1) s += __shfl_xor(s, off);
        if (t == 0) bsum[blockIdx.x] = s;
    }
}

__global__ __launch_bounds__(1024) void bscan_kernel(int* __restrict__ bsum, int NB,
                                                     int* __restrict__ rowstart, int N)
{
    __shared__ int wsum[16];
    const int t = threadIdx.x, lane = t & 63, wid = t >> 6;
    const int v = (t < NB) ? bsum[t] : 0;
    int s = v;
    #pragma unroll
    for (int off = 1; off < 64; off <<= 1) {
        int u = __shfl_up(s, off);
        if (lane >= off) s += u;
    }
    if (lane == 63) wsum[wid] = s;
    __syncthreads();
    if (wid == 0 && lane < 16) {
        int ss = wsum[lane];
        #pragma unroll
        for (int off = 1; off < 16; off <<= 1) {
            int u = __shfl_up(ss, off);
            if (lane >= off) ss += u;
        }
        wsum[lane] = ss;
    }
    __syncthreads();
    const int woff = (wid == 0) ? 0 : wsum[wid - 1];
    if (t < NB) bsum[t] = s + woff - v;
    if (t == 1023) rowstart[N] = s + woff;
}

__global__ __launch_bounds__(1024) void scan_apply_kernel(
    const int* __restrict__ deg, const int* __restrict__ bsum, int N,
    int* __restrict__ rowstart, int* __restrict__ cursor)
{
    __shared__ int wsum[16];
    const int t = threadIdx.x, lane = t & 63, wid = t >> 6;
    const int idx = blockIdx.x * 1024 + t;
    const int v = (idx < N) ? deg[idx] : 0;
    int s = v;
    #pragma unroll
    for (int off = 1; off < 64; off <<= 1) {
        int u = __shfl_up(s, off);
        if (lane >= off) s += u;
    }
    if (lane == 63) wsum[wid] = s;
    __syncthreads();
    if (wid == 0 && lane < 16) {
        int ss = wsum[lane];
        #pragma unroll
        for (int off = 1; off < 16; off <<= 1) {
            int u = __shfl_up(ss, off);
            if (lane >= off) ss += u;
        }
        wsum[lane] = ss;
    }
    __syncthreads();
    const int woff = (wid == 0) ? 0 : wsum[wid - 1];
    const int excl = s + woff - v + bsum[blockIdx.x];
    if (idx < N) { rowstart[idx] = excl; cursor[idx] = excl; }
}

// ---------------- CSR fill ----------------
__global__ __launch_bounds__(256) void fill_kernel(const int* __restrict__ ei, int E,
                                                   int* __restrict__ cursor,
                                                   int* __restrict__ csr_col)
{
    const int e = blockIdx.x * 256 + threadIdx.x;
    if (e < E) {
        const int rr = ei[e];
        const int pos = atomicAdd(&cursor[rr], 1);
        csr_col[pos] = ei[E + e];
    }
}

// ---------------- fused attention: 4 edges/wave, 1-deep pipelined ------------
// lane: g=l>>4 edge slot, h=(l>>2)&3 head, dr=l&3 -> dims [dr*16, dr*16+16)
__global__ __launch_bounds__(256) void attn_kernel(
    const unsigned short* __restrict__ QL, const unsigned short* __restrict__ KH,
    const int* __restrict__ rowstart, const int* __restrict__ csr_col,
    float* __restrict__ out, int N)
{
    const int n = blockIdx.x * 4 + (threadIdx.x >> 6);
    if (n >= N) return;
    const int l  = threadIdx.x & 63;
    const int g  = l >> 4;
    const int koff = ((l >> 2) & 3) * 64 + (l & 3) * 16;   // h*64 + dr*16 (shorts)

    float qf[16];
    {
        const uint4* qp = (const uint4*)(QL + (size_t)n * FEAT + koff);
        const uint4 q0 = qp[0], q1 = qp[1];
        unsigned qs[8] = {q0.x, q0.y, q0.z, q0.w, q1.x, q1.y, q1.z, q1.w};
        #pragma unroll
        for (int tt = 0; tt < 8; ++tt) {
            qf[2 * tt]     = bflo(qs[tt]);
            qf[2 * tt + 1] = bfhi(qs[tt]);
        }
    }

    const int s0 = rowstart[n];
    const int s1 = rowstart[n + 1];

    float acc[16];
    #pragma unroll
    for (int j = 0; j < 16; ++j) acc[j] = 0.f;
    float z = 0.f;

    if (s0 < s1) {
        // prologue: load group 0 (clamped slot -> masked later)
        int eidx = s0 + g;
        float vmask = (eidx < s1) ? 1.f : 0.f;
        int c = csr_col[(eidx < s1) ? eidx : s0];
        const uint4* kp = (const uint4*)(KH + (size_t)c * KHROW + koff);
        uint4 k0 = kp[0], k1 = kp[1], h0 = kp[32], h1 = kp[33];

        for (int i = s0; i < s1; i += 4) {
            // prefetch next group (wave-uniform branch: i,s1 uniform)
            uint4 nk0, nk1, nh0, nh1;
            float nmask = 0.f;
            if (i + 4 < s1) {
                const int ne = i + 4 + g;
                nmask = (ne < s1) ? 1.f : 0.f;
                const int nc = csr_col[(ne < s1) ? ne : s0];
                const uint4* np = (const uint4*)(KH + (size_t)nc * KHROW + koff);
                nk0 = np[0]; nk1 = np[1]; nh0 = np[32]; nh1 = np[33];
            }

            // compute current group
            unsigned ks[8] = {k0.x, k0.y, k0.z, k0.w, k1.x, k1.y, k1.z, k1.w};
            float p = 0.f;
            #pragma unroll
            for (int tt = 0; tt < 8; ++tt) {
                p = fmaf(qf[2 * tt],     bflo(ks[tt]), p);
                p = fmaf(qf[2 * tt + 1], bfhi(ks[tt]), p);
            }
            p += __shfl_xor(p, 1);
            p += __shfl_xor(p, 2);

            const float e = vmask * __expf(p * 0.125f);  // no-max softmax
            z += e;
            unsigned hs[8] = {h0.x, h0.y, h0.z, h0.w, h1.x, h1.y, h1.z, h1.w};
            #pragma unroll
            for (int tt = 0; tt < 8; ++tt) {
                acc[2 * tt]     = fmaf(e, bflo(hs[tt]), acc[2 * tt]);
                acc[2 * tt + 1] = fmaf(e, bfhi(hs[tt]), acc[2 * tt + 1]);
            }

            k0 = nk0; k1 = nk1; h0 = nh0; h1 = nh1; vmask = nmask;
        }
    }

    // sum across the 4 edge slots
    z += __shfl_xor(z, 16);
    z += __shfl_xor(z, 32);
    #pragma unroll
    for (int j = 0; j < 16; ++j) {
        acc[j] += __shfl_xor(acc[j], 16);
        acc[j] += __shfl_xor(acc[j], 32);
    }
    // normalize per head, then mean over heads
    const float inv = 0.25f / (z + 1e-8f);
    #pragma unroll
    for (int j = 0; j < 16; ++j) {
        float r = acc[j] * inv;
        r += __shfl_xor(r, 4);
        r += __shfl_xor(r, 8);
        acc[j] = r;
    }
    if (l < 4) {
        float* ob = out + (size_t)n * NOUT + l * 16;
        *(float4*)(ob + 0)  = make_float4(acc[0],  acc[1],  acc[2],  acc[3]);
        *(float4*)(ob + 4)  = make_float4(acc[4],  acc[5],  acc[6],  acc[7]);
        *(float4*)(ob + 8)  = make_float4(acc[8],  acc[9],  acc[10], acc[11]);
        *(float4*)(ob + 12) = make_float4(acc[12], acc[13], acc[14], acc[15]);
    }
}

// ---------------- launch ----------------
extern "C" void kernel_launch(void* const* d_in, const int* in_sizes, int n_in,
                              void* d_out, int out_size, void* d_ws, size_t ws_size,
                              hipStream_t stream)
{
    const float* x  = (const float*)d_in[0];
    const int*   ei = (const int*)d_in[1];
    const float* Wq = (const float*)d_in[2];
    const float* Wk = (const float*)d_in[3];
    const float* Wh = (const float*)d_in[4];
    const float* bh = (const float*)d_in[5];
    float* out = (float*)d_out;
    const int N = in_sizes[0] / NIN;   // 100000
    const int E = in_sizes[1] / 2;     // 1600000

    char* p = (char*)d_ws;
    auto alloc = [&](size_t bytes) {
        char* r = p;
        p += (bytes + 255) & ~(size_t)255;
        return r;
    };
    unsigned short* QL  = (unsigned short*)alloc((size_t)N * FEAT * 2);
    unsigned short* KH  = (unsigned short*)alloc((size_t)N * KHROW * 2);
    unsigned short* Wsw = (unsigned short*)alloc((size_t)12288 * 8 * 2);
    int* deg      = (int*)alloc((size_t)N * 4);
    int* rowstart = (int*)alloc((size_t)(N + 1) * 4);
    int* cursor   = (int*)alloc((size_t)N * 4);
    int* csr_col  = (int*)alloc((size_t)(E + 8) * 4);  // +pad for clamped reads
    int* bsum     = (int*)alloc((size_t)1024 * 4);

    const int NB = (N + 1023) / 1024;   // 98

    hipMemsetAsync(deg, 0, (size_t)N * 4, stream);

    wconv_kernel<<<48, 256, 0, stream>>>(Wq, Wk, Wh, Wsw);
    gemm_mfma_kernel<<<(N + 63) / 64, 256, 0, stream>>>(x, Wsw, bh, QL, KH, N);
    deg_kernel<<<(E + 255) / 256, 256, 0, stream>>>(ei, E, deg);
    bsum_kernel<<<NB, 1024, 0, stream>>>(deg, N, bsum);
    bscan_kernel<<<1, 1024, 0, stream>>>(bsum, NB, rowstart, N);
    scan_apply_kernel<<<NB, 1024, 0, stream>>>(deg, bsum, N, rowstart, cursor);
    fill_kernel<<<(E + 255) / 256, 256, 0, stream>>>(ei, E, cursor, csr_col);
    attn_kernel<<<(N + 3) / 4, 256, 0, stream>>>(QL, KH, rowstart, csr_col, out, N);
}

// Round 8
// 454.367 us; speedup vs baseline: 1.1773x; 1.1773x over previous
//
#include <hip/hip_runtime.h>
#include <math.h>

#define NIN 128
#define NOUT 64
#define FEAT 256        // QL row: 256 bf16 = 512B
#define KHROW 512       // KH row: K(256 bf16) | H(256 bf16) = 1024B

typedef __attribute__((ext_vector_type(8))) short short8;
typedef __attribute__((ext_vector_type(4))) float f32x4;

__device__ __forceinline__ unsigned short f2bf(float f) {
    unsigned u = __float_as_uint(f);
    u = (u + 0x7FFFu + ((u >> 16) & 1u)) >> 16;   // RTNE
    return (unsigned short)u;
}
__device__ __forceinline__ float bflo(unsigned u) {
    return __uint_as_float(u << 16);
}
__device__ __forceinline__ float bfhi(unsigned u) {
    return __uint_as_float(u & 0xffff0000u);
}

// ---------------- W fp32 -> bf16, pre-swizzled to MFMA A-fragment order ------
// Wsw[(mat*4+head)*4+tile][kb][lane][8]: element = W[mat][head][tile*16+(lane&15)]
//                                                 [kb*32+(lane>>4)*8 + j]
__global__ __launch_bounds__(256) void wconv_kernel(
    const float* __restrict__ Wq, const float* __restrict__ Wk,
    const float* __restrict__ Wh, unsigned short* __restrict__ Wsw)
{
    const int id = blockIdx.x * 256 + threadIdx.x;   // 12288 total
    const int lane = id & 63;
    const int kb   = (id >> 6) & 3;
    const int tile = (id >> 8) & 3;
    const int head = (id >> 10) & 3;
    const int mat  = id >> 12;
    const float* src = (mat == 0) ? Wq : (mat == 1) ? Wk : Wh;
    const int row   = tile * 16 + (lane & 15);
    const int kbase = kb * 32 + (lane >> 4) * 8;
    const float* sp = src + (size_t)(head * 64 + row) * NIN + kbase;
    const float4 a = *(const float4*)sp;
    const float4 b = *(const float4*)(sp + 4);
    uint4 w;
    w.x = (unsigned)f2bf(a.x) | ((unsigned)f2bf(a.y) << 16);
    w.y = (unsigned)f2bf(a.z) | ((unsigned)f2bf(a.w) << 16);
    w.z = (unsigned)f2bf(b.x) | ((unsigned)f2bf(b.y) << 16);
    w.w = (unsigned)f2bf(b.z) | ((unsigned)f2bf(b.w) << 16);
    *(uint4*)(Wsw + (size_t)id * 8) = w;
}

// ---------------- MFMA GEMM (BM=128) + fused degree count --------------------
// gemm blocks [0,GB): A=W, B=x -> D col=node(l&15), row=feature((l>>4)*4+i).
// Epilogue bounces through wave-private LDS for 1KB-contiguous stores.
// blocks [GB, GB+512): degree count for the CSR build (independent work).
__global__ __launch_bounds__(256) void gemm_mfma_kernel(
    const float* __restrict__ x, const unsigned short* __restrict__ Wsw,
    const float* __restrict__ bh,
    unsigned short* __restrict__ QL, unsigned short* __restrict__ KH, int N,
    const int* __restrict__ ei, int E, int* __restrict__ deg, int GB)
{
    if (blockIdx.x >= GB) {   // ---- degree-count side job ----
        for (int e = (blockIdx.x - GB) * 256 + threadIdx.x; e < E; e += 512 * 256)
            atomicAdd(&deg[ei[e]], 1);
        return;
    }

    __shared__ char smem[128 * 136 * 2];   // xs staging, then per-wave bounce
    unsigned short (*xs)[136] = (unsigned short (*)[136])smem;

    const int nb = blockIdx.x * 128;
    const int t  = threadIdx.x;
    const int w  = t >> 6;
    const int l  = t & 63;

    // stage x tile: fp32 -> bf16 (128 rows x 32 float4)
    #pragma unroll
    for (int j = 0; j < 16; ++j) {
        const int idx = j * 256 + t;
        const int row = idx >> 5;
        const int c4  = idx & 31;
        float4 xv = make_float4(0.f, 0.f, 0.f, 0.f);
        if (nb + row < N)
            xv = *(const float4*)(x + (size_t)(nb + row) * NIN + c4 * 4);
        ushort4 pk;
        pk.x = f2bf(xv.x); pk.y = f2bf(xv.y); pk.z = f2bf(xv.z); pk.w = f2bf(xv.w);
        *(ushort4*)(&xs[row][c4 * 4]) = pk;
    }
    __syncthreads();

    // B-fragments: wave w owns nodes [w*32, w*32+32) as two 16-node sets
    short8 bfrx[2][4];
    #pragma unroll
    for (int ns = 0; ns < 2; ++ns)
        #pragma unroll
        for (int kb = 0; kb < 4; ++kb)
            bfrx[ns][kb] = *(const short8*)(
                &xs[w * 32 + ns * 16 + (l & 15)][kb * 32 + (l >> 4) * 8]);
    __syncthreads();   // all waves done reading xs; safe to reuse as bounce

    char* const sbw = smem + w * 4608;     // wave-private: 32 nodes x 144B
    const int fsub = (l >> 4) * 4;

    for (int g = 0; g < 12; ++g) {
        const int mat  = g >> 2;
        const int head = g & 3;

        #pragma unroll
        for (int tile = 0; tile < 4; ++tile) {
            f32x4 a0 = (f32x4){0.f, 0.f, 0.f, 0.f};
            f32x4 a1 = (f32x4){0.f, 0.f, 0.f, 0.f};
            #pragma unroll
            for (int kb = 0; kb < 4; ++kb) {
                const short8 afrw = *(const short8*)(
                    Wsw + ((size_t)((g * 4 + tile) * 4 + kb) << 9) + (l << 3));
                a0 = __builtin_amdgcn_mfma_f32_16x16x32_bf16(afrw, bfrx[0][kb], a0, 0, 0, 0);
                a1 = __builtin_amdgcn_mfma_f32_16x16x32_bf16(afrw, bfrx[1][kb], a1, 0, 0, 0);
            }
            #pragma unroll
            for (int ns = 0; ns < 2; ++ns) {
                const f32x4 av = ns ? a1 : a0;
                float v0 = av[0], v1 = av[1], v2 = av[2], v3 = av[3];
                const int node = (l & 15) + ns * 16;
                if (mat == 2) {
                    const float4 bv = *(const float4*)(bh + head * NOUT + tile * 16 + fsub);
                    v0 += bv.x; v1 += bv.y; v2 += bv.z; v3 += bv.w;
                } else {
                    v0 = (v0 > 0.f) ? v0 : 0.2f * v0;
                    v1 = (v1 > 0.f) ? v1 : 0.2f * v1;
                    v2 = (v2 > 0.f) ? v2 : 0.2f * v2;
                    v3 = (v3 > 0.f) ? v3 : 0.2f * v3;
                }
                uint2 pk;
                pk.x = (unsigned)f2bf(v0) | ((unsigned)f2bf(v1) << 16);
                pk.y = (unsigned)f2bf(v2) | ((unsigned)f2bf(v3) << 16);
                *(uint2*)(sbw + node * 144 + (tile * 16 + fsub) * 2) = pk;
            }
        }

        // store: 8 nodes per instruction, 1KB fully-contiguous per wave op
        #pragma unroll
        for (int jj = 0; jj < 4; ++jj) {
            const int node  = (l >> 3) + jj * 8;
            const int gnode = nb + w * 32 + node;
            const uint4 v = *(const uint4*)(sbw + node * 144 + (l & 7) * 16);
            if (gnode < N) {
                char* ob;
                if (mat == 0)      ob = (char*)QL + (size_t)gnode * 512 + head * 128;
                else if (mat == 1) ob = (char*)KH + (size_t)gnode * 1024 + head * 128;
                else               ob = (char*)KH + (size_t)gnode * 1024 + 512 + head * 128;
                *(uint4*)(ob + (l & 7) * 16) = v;
            }
        }
    }
}

// ---------------- multi-block scan ----------------
__global__ __launch_bounds__(1024) void bsum_kernel(const int* __restrict__ deg, int N,
                                                    int* __restrict__ bsum)
{
    __shared__ int wsum[16];
    const int t = threadIdx.x;
    const int idx = blockIdx.x * 1024 + t;
    int v = (idx < N) ? deg[idx] : 0;
    #pragma unroll
    for (int off = 1; off < 64; off <<= 1) v += __shfl_xor(v, off);
    if ((t & 63) == 0) wsum[t >> 6] = v;
    __syncthreads();
    if (t < 16) {
        int s = wsum[t];
        #pragma unroll
        for (int off = 1; off < 16; off <<= 1) s += __shfl_xor(s, off);
        if (t == 0) bsum[blockIdx.x] = s;
    }
}

__global__ __launch_bounds__(1024) void bscan_kernel(int* __restrict__ bsum, int NB,
                                                     int* __restrict__ rowstart, int N)
{
    __shared__ int wsum[16];
    const int t = threadIdx.x, lane = t & 63, wid = t >> 6;
    const int v = (t < NB) ? bsum[t] : 0;
    int s = v;
    #pragma unroll
    for (int off = 1; off < 64; off <<= 1) {
        int u = __shfl_up(s, off);
        if (lane >= off) s += u;
    }
    if (lane == 63) wsum[wid] = s;
    __syncthreads();
    if (wid == 0 && lane < 16) {
        int ss = wsum[lane];
        #pragma unroll
        for (int off = 1; off < 16; off <<= 1) {
            int u = __shfl_up(ss, off);
            if (lane >= off) ss += u;
        }
        wsum[lane] = ss;
    }
    __syncthreads();
    const int woff = (wid == 0) ? 0 : wsum[wid - 1];
    if (t < NB) bsum[t] = s + woff - v;
    if (t == 1023) rowstart[N] = s + woff;
}

__global__ __launch_bounds__(1024) void scan_apply_kernel(
    const int* __restrict__ deg, const int* __restrict__ bsum, int N,
    int* __restrict__ rowstart, int* __restrict__ cursor)
{
    __shared__ int wsum[16];
    const int t = threadIdx.x, lane = t & 63, wid = t >> 6;
    const int idx = blockIdx.x * 1024 + t;
    const int v = (idx < N) ? deg[idx] : 0;
    int s = v;
    #pragma unroll
    for (int off = 1; off < 64; off <<= 1) {
        int u = __shfl_up(s, off);
        if (lane >= off) s += u;
    }
    if (lane == 63) wsum[wid] = s;
    __syncthreads();
    if (wid == 0 && lane < 16) {
        int ss = wsum[lane];
        #pragma unroll
        for (int off = 1; off < 16; off <<= 1) {
            int u = __shfl_up(ss, off);
            if (lane >= off) ss += u;
        }
        wsum[lane] = ss;
    }
    __syncthreads();
    const int woff = (wid == 0) ? 0 : wsum[wid - 1];
    const int excl = s + woff - v + bsum[blockIdx.x];
    if (idx < N) { rowstart[idx] = excl; cursor[idx] = excl; }
}

// ---------------- CSR fill ----------------
__global__ __launch_bounds__(256) void fill_kernel(const int* __restrict__ ei, int E,
                                                   int* __restrict__ cursor,
                                                   int* __restrict__ csr_col)
{
    const int e = blockIdx.x * 256 + threadIdx.x;
    if (e < E) {
        const int rr = ei[e];
        const int pos = atomicAdd(&cursor[rr], 1);
        csr_col[pos] = ei[E + e];
    }
}

// ---------------- fused attention: 4 edges/wave, 16 lanes/edge --------------
// lane: g=l>>4 edge slot, h=(l>>2)&3 head, dr=l&3 -> dims [dr*16, dr*16+16)
__global__ __launch_bounds__(256) void attn_kernel(
    const unsigned short* __restrict__ QL, const unsigned short* __restrict__ KH,
    const int* __restrict__ rowstart, const int* __restrict__ csr_col,
    float* __restrict__ out, int N)
{
    const int n = blockIdx.x * 4 + (threadIdx.x >> 6);
    if (n >= N) return;
    const int l  = threadIdx.x & 63;
    const int g  = l >> 4;
    const int koff = ((l >> 2) & 3) * 64 + (l & 3) * 16;   // h*64 + dr*16 (shorts)

    // Q fragment: 16 dims of (h, dr)
    float qf[16];
    {
        const uint4* qp = (const uint4*)(QL + (size_t)n * FEAT + koff);
        const uint4 q0 = qp[0], q1 = qp[1];
        unsigned qs[8] = {q0.x, q0.y, q0.z, q0.w, q1.x, q1.y, q1.z, q1.w};
        #pragma unroll
        for (int tt = 0; tt < 8; ++tt) {
            qf[2 * tt]     = bflo(qs[tt]);
            qf[2 * tt + 1] = bfhi(qs[tt]);
        }
    }

    const int s0 = rowstart[n];
    const int s1 = rowstart[n + 1];

    float acc[16];
    #pragma unroll
    for (int j = 0; j < 16; ++j) acc[j] = 0.f;
    float z = 0.f;

    for (int i = s0; i < s1; i += 4) {
        const int eidx = i + g;
        if (eidx < s1) {
            const int c = csr_col[eidx];
            const uint4* kp = (const uint4*)(KH + (size_t)c * KHROW + koff);
            const uint4 k0 = kp[0],  k1 = kp[1];     // 32B of K
            const uint4 h0 = kp[32], h1 = kp[33];    // 32B of H (+256 shorts)

            unsigned ks[8] = {k0.x, k0.y, k0.z, k0.w, k1.x, k1.y, k1.z, k1.w};
            float p = 0.f;
            #pragma unroll
            for (int tt = 0; tt < 8; ++tt) {
                p = fmaf(qf[2 * tt],     bflo(ks[tt]), p);
                p = fmaf(qf[2 * tt + 1], bfhi(ks[tt]), p);
            }
            // reduce across the 4 dr lanes
            p += __shfl_xor(p, 1);
            p += __shfl_xor(p, 2);

            const float e = __expf(p * 0.125f);   // no-max softmax (shift-inv.)
            z += e;
            unsigned hs[8] = {h0.x, h0.y, h0.z, h0.w, h1.x, h1.y, h1.z, h1.w};
            #pragma unroll
            for (int tt = 0; tt < 8; ++tt) {
                acc[2 * tt]     = fmaf(e, bflo(hs[tt]), acc[2 * tt]);
                acc[2 * tt + 1] = fmaf(e, bfhi(hs[tt]), acc[2 * tt + 1]);
            }
        }
    }

    // sum across the 4 edge slots
    z += __shfl_xor(z, 16);
    z += __shfl_xor(z, 32);
    #pragma unroll
    for (int j = 0; j < 16; ++j) {
        acc[j] += __shfl_xor(acc[j], 16);
        acc[j] += __shfl_xor(acc[j], 32);
    }
    // normalize per head, then mean over heads
    const float inv = 0.25f / (z + 1e-8f);
    #pragma unroll
    for (int j = 0; j < 16; ++j) {
        float r = acc[j] * inv;
        r += __shfl_xor(r, 4);
        r += __shfl_xor(r, 8);
        acc[j] = r;
    }
    if (l < 4) {   // g=0,h=0, dr=l: dims [l*16, l*16+16)
        float* ob = out + (size_t)n * NOUT + l * 16;
        *(float4*)(ob + 0)  = make_float4(acc[0],  acc[1],  acc[2],  acc[3]);
        *(float4*)(ob + 4)  = make_float4(acc[4],  acc[5],  acc[6],  acc[7]);
        *(float4*)(ob + 8)  = make_float4(acc[8],  acc[9],  acc[10], acc[11]);
        *(float4*)(ob + 12) = make_float4(acc[12], acc[13], acc[14], acc[15]);
    }
}

// ---------------- launch ----------------
extern "C" void kernel_launch(void* const* d_in, const int* in_sizes, int n_in,
                              void* d_out, int out_size, void* d_ws, size_t ws_size,
                              hipStream_t stream)
{
    const float* x  = (const float*)d_in[0];
    const int*   ei = (const int*)d_in[1];
    const float* Wq = (const float*)d_in[2];
    const float* Wk = (const float*)d_in[3];
    const float* Wh = (const float*)d_in[4];
    const float* bh = (const float*)d_in[5];
    float* out = (float*)d_out;
    const int N = in_sizes[0] / NIN;   // 100000
    const int E = in_sizes[1] / 2;     // 1600000

    char* p = (char*)d_ws;
    auto alloc = [&](size_t bytes) {
        char* r = p;
        p += (bytes + 255) & ~(size_t)255;
        return r;
    };
    unsigned short* QL  = (unsigned short*)alloc((size_t)N * FEAT * 2);
    unsigned short* KH  = (unsigned short*)alloc((size_t)N * KHROW * 2);
    unsigned short* Wsw = (unsigned short*)alloc((size_t)12288 * 8 * 2);
    int* deg      = (int*)alloc((size_t)N * 4);
    int* rowstart = (int*)alloc((size_t)(N + 1) * 4);
    int* cursor   = (int*)alloc((size_t)N * 4);
    int* csr_col  = (int*)alloc((size_t)(E + 8) * 4);
    int* bsum     = (int*)alloc((size_t)1024 * 4);

    const int NB = (N + 1023) / 1024;   // 98
    const int GB = (N + 127) / 128;     // 782 gemm blocks

    hipMemsetAsync(deg, 0, (size_t)N * 4, stream);

    wconv_kernel<<<48, 256, 0, stream>>>(Wq, Wk, Wh, Wsw);
    gemm_mfma_kernel<<<GB + 512, 256, 0, stream>>>(x, Wsw, bh, QL, KH, N,
                                                   ei, E, deg, GB);
    bsum_kernel<<<NB, 1024, 0, stream>>>(deg, N, bsum);
    bscan_kernel<<<1, 1024, 0, stream>>>(bsum, NB, rowstart, N);
    scan_apply_kernel<<<NB, 1024, 0, stream>>>(deg, bsum, N, rowstart, cursor);
    fill_kernel<<<(E + 255) / 256, 256, 0, stream>>>(ei, E, cursor, csr_col);
    attn_kernel<<<(N + 3) / 4, 256, 0, stream>>>(QL, KH, rowstart, csr_col, out, N);
}

// Round 9
// 357.813 us; speedup vs baseline: 1.4950x; 1.2698x over previous
//
#include <hip/hip_runtime.h>
#include <math.h>

#define NIN 128
#define NOUT 64
#define FEAT 256        // QL row: 256 bf16 = 512B
#define KHROW 512       // KH row: K(256 bf16) | H(256 bf16) = 1024B

typedef __attribute__((ext_vector_type(8))) short short8;
typedef __attribute__((ext_vector_type(4))) float f32x4;

__device__ __forceinline__ unsigned short f2bf(float f) {
    unsigned u = __float_as_uint(f);
    u = (u + 0x7FFFu + ((u >> 16) & 1u)) >> 16;   // RTNE
    return (unsigned short)u;
}
__device__ __forceinline__ float bflo(unsigned u) {
    return __uint_as_float(u << 16);
}
__device__ __forceinline__ float bfhi(unsigned u) {
    return __uint_as_float(u & 0xffff0000u);
}

// ---------------- W fp32 -> bf16, pre-swizzled to MFMA A-fragment order ------
// Wsw[(mat*4+head)*4+tile][kb][lane][8]: element = W[mat][head][tile*16+(lane&15)]
//                                                 [kb*32+(lane>>4)*8 + j]
__global__ __launch_bounds__(256) void wconv_kernel(
    const float* __restrict__ Wq, const float* __restrict__ Wk,
    const float* __restrict__ Wh, unsigned short* __restrict__ Wsw)
{
    const int id = blockIdx.x * 256 + threadIdx.x;   // 12288 total
    const int lane = id & 63;
    const int kb   = (id >> 6) & 3;
    const int tile = (id >> 8) & 3;
    const int head = (id >> 10) & 3;
    const int mat  = id >> 12;
    const float* src = (mat == 0) ? Wq : (mat == 1) ? Wk : Wh;
    const int row   = tile * 16 + (lane & 15);
    const int kbase = kb * 32 + (lane >> 4) * 8;
    const float* sp = src + (size_t)(head * 64 + row) * NIN + kbase;
    const float4 a = *(const float4*)sp;
    const float4 b = *(const float4*)(sp + 4);
    uint4 w;
    w.x = (unsigned)f2bf(a.x) | ((unsigned)f2bf(a.y) << 16);
    w.y = (unsigned)f2bf(a.z) | ((unsigned)f2bf(a.w) << 16);
    w.z = (unsigned)f2bf(b.x) | ((unsigned)f2bf(b.y) << 16);
    w.w = (unsigned)f2bf(b.z) | ((unsigned)f2bf(b.w) << 16);
    *(uint4*)(Wsw + (size_t)id * 8) = w;
}

// ---------------- MFMA GEMM (BM=128, W staged via LDS) + fused degree/epos ---
// gemm blocks [0,GB): A=W, B=x -> D col=node(l&15), row=feature((l>>4)*4+i).
// blocks [GB, GB+512): degree count + per-edge position for the CSR build.
__global__ __launch_bounds__(256) void gemm_mfma_kernel(
    const float* __restrict__ x, const unsigned short* __restrict__ Wsw,
    const float* __restrict__ bh,
    unsigned short* __restrict__ QL, unsigned short* __restrict__ KH, int N,
    const int* __restrict__ ei, int E, int* __restrict__ deg,
    int* __restrict__ epos, int GB)
{
    if (blockIdx.x >= GB) {   // ---- degree-count + edge-position side job ----
        for (int e = (blockIdx.x - GB) * 256 + threadIdx.x; e < E; e += 512 * 256)
            epos[e] = atomicAdd(&deg[ei[e]], 1);
        return;
    }

    __shared__ char smem[34816];   // [0,34816) xs; then [0,18432) bounce | [18432,34816) W
    unsigned short (*xs)[136] = (unsigned short (*)[136])smem;

    const int nb = blockIdx.x * 128;
    const int t  = threadIdx.x;
    const int w  = t >> 6;
    const int l  = t & 63;

    // stage x tile: fp32 -> bf16 (128 rows x 32 float4)
    #pragma unroll
    for (int j = 0; j < 16; ++j) {
        const int idx = j * 256 + t;
        const int row = idx >> 5;
        const int c4  = idx & 31;
        float4 xv = make_float4(0.f, 0.f, 0.f, 0.f);
        if (nb + row < N)
            xv = *(const float4*)(x + (size_t)(nb + row) * NIN + c4 * 4);
        ushort4 pk;
        pk.x = f2bf(xv.x); pk.y = f2bf(xv.y); pk.z = f2bf(xv.z); pk.w = f2bf(xv.w);
        *(ushort4*)(&xs[row][c4 * 4]) = pk;
    }
    __syncthreads();

    // B-fragments: wave w owns nodes [w*32, w*32+32) as two 16-node sets
    short8 bfrx[2][4];
    #pragma unroll
    for (int ns = 0; ns < 2; ++ns)
        #pragma unroll
        for (int kb = 0; kb < 4; ++kb)
            bfrx[ns][kb] = *(const short8*)(
                &xs[w * 32 + ns * 16 + (l & 15)][kb * 32 + (l >> 4) * 8]);
    __syncthreads();   // all waves done reading xs; reuse as bounce + W stage

    char* const sbw = smem + w * 4608;                       // 32 nodes x 144B
    unsigned short* const wl = (unsigned short*)(smem + 18432);  // 16KB W stage
    const int fsub = (l >> 4) * 4;

    for (int g = 0; g < 12; ++g) {
        const int mat  = g >> 2;
        const int head = g & 3;

        // cooperative stage of this group's 16KB of W (each thread 4x16B)
        {
            const uint4* gw = (const uint4*)(Wsw + (size_t)g * 8192);
            uint4* wl4 = (uint4*)wl;
            #pragma unroll
            for (int j = 0; j < 4; ++j)
                wl4[j * 256 + t] = gw[j * 256 + t];
        }
        __syncthreads();   // W visible to all waves

        #pragma unroll
        for (int tile = 0; tile < 4; ++tile) {
            f32x4 a0 = (f32x4){0.f, 0.f, 0.f, 0.f};
            f32x4 a1 = (f32x4){0.f, 0.f, 0.f, 0.f};
            #pragma unroll
            for (int kb = 0; kb < 4; ++kb) {
                const short8 afrw = *(const short8*)(
                    wl + (((tile * 4 + kb) << 9) + (l << 3)));
                a0 = __builtin_amdgcn_mfma_f32_16x16x32_bf16(afrw, bfrx[0][kb], a0, 0, 0, 0);
                a1 = __builtin_amdgcn_mfma_f32_16x16x32_bf16(afrw, bfrx[1][kb], a1, 0, 0, 0);
            }
            #pragma unroll
            for (int ns = 0; ns < 2; ++ns) {
                const f32x4 av = ns ? a1 : a0;
                float v0 = av[0], v1 = av[1], v2 = av[2], v3 = av[3];
                const int node = (l & 15) + ns * 16;
                if (mat == 2) {
                    const float4 bv = *(const float4*)(bh + head * NOUT + tile * 16 + fsub);
                    v0 += bv.x; v1 += bv.y; v2 += bv.z; v3 += bv.w;
                } else {
                    v0 = (v0 > 0.f) ? v0 : 0.2f * v0;
                    v1 = (v1 > 0.f) ? v1 : 0.2f * v1;
                    v2 = (v2 > 0.f) ? v2 : 0.2f * v2;
                    v3 = (v3 > 0.f) ? v3 : 0.2f * v3;
                }
                uint2 pk;
                pk.x = (unsigned)f2bf(v0) | ((unsigned)f2bf(v1) << 16);
                pk.y = (unsigned)f2bf(v2) | ((unsigned)f2bf(v3) << 16);
                *(uint2*)(sbw + node * 144 + (tile * 16 + fsub) * 2) = pk;
            }
        }

        // store: 8 nodes per instruction, 1KB fully-contiguous per wave op
        #pragma unroll
        for (int jj = 0; jj < 4; ++jj) {
            const int node  = (l >> 3) + jj * 8;
            const int gnode = nb + w * 32 + node;
            const uint4 v = *(const uint4*)(sbw + node * 144 + (l & 7) * 16);
            if (gnode < N) {
                char* ob;
                if (mat == 0)      ob = (char*)QL + (size_t)gnode * 512 + head * 128;
                else if (mat == 1) ob = (char*)KH + (size_t)gnode * 1024 + head * 128;
                else               ob = (char*)KH + (size_t)gnode * 1024 + 512 + head * 128;
                *(uint4*)(ob + (l & 7) * 16) = v;
            }
        }
        __syncthreads();   // done reading wl before next group's stage
    }
}

// ---------------- multi-block scan ----------------
__global__ __launch_bounds__(1024) void bsum_kernel(const int* __restrict__ deg, int N,
                                                    int* __restrict__ bsum)
{
    __shared__ int wsum[16];
    const int t = threadIdx.x;
    const int idx = blockIdx.x * 1024 + t;
    int v = (idx < N) ? deg[idx] : 0;
    #pragma unroll
    for (int off = 1; off < 64; off <<= 1) v += __shfl_xor(v, off);
    if ((t & 63) == 0) wsum[t >> 6] = v;
    __syncthreads();
    if (t < 16) {
        int s = wsum[t];
        #pragma unroll
        for (int off = 1; off < 16; off <<= 1) s += __shfl_xor(s, off);
        if (t == 0) bsum[blockIdx.x] = s;
    }
}

__global__ __launch_bounds__(1024) void bscan_kernel(int* __restrict__ bsum, int NB,
                                                     int* __restrict__ rowstart, int N)
{
    __shared__ int wsum[16];
    const int t = threadIdx.x, lane = t & 63, wid = t >> 6;
    const int v = (t < NB) ? bsum[t] : 0;
    int s = v;
    #pragma unroll
    for (int off = 1; off < 64; off <<= 1) {
        int u = __shfl_up(s, off);
        if (lane >= off) s += u;
    }
    if (lane == 63) wsum[wid] = s;
    __syncthreads();
    if (wid == 0 && lane < 16) {
        int ss = wsum[lane];
        #pragma unroll
        for (int off = 1; off < 16; off <<= 1) {
            int u = __shfl_up(ss, off);
            if (lane >= off) ss += u;
        }
        wsum[lane] = ss;
    }
    __syncthreads();
    const int woff = (wid == 0) ? 0 : wsum[wid - 1];
    if (t < NB) bsum[t] = s + woff - v;
    if (t == 1023) rowstart[N] = s + woff;
}

__global__ __launch_bounds__(1024) void scan_apply_kernel(
    const int* __restrict__ deg, const int* __restrict__ bsum, int N,
    int* __restrict__ rowstart)
{
    __shared__ int wsum[16];
    const int t = threadIdx.x, lane = t & 63, wid = t >> 6;
    const int idx = blockIdx.x * 1024 + t;
    const int v = (idx < N) ? deg[idx] : 0;
    int s = v;
    #pragma unroll
    for (int off = 1; off < 64; off <<= 1) {
        int u = __shfl_up(s, off);
        if (lane >= off) s += u;
    }
    if (lane == 63) wsum[wid] = s;
    __syncthreads();
    if (wid == 0 && lane < 16) {
        int ss = wsum[lane];
        #pragma unroll
        for (int off = 1; off < 16; off <<= 1) {
            int u = __shfl_up(ss, off);
            if (lane >= off) ss += u;
        }
        wsum[lane] = ss;
    }
    __syncthreads();
    const int woff = (wid == 0) ? 0 : wsum[wid - 1];
    if (idx < N) rowstart[idx] = s + woff - v + bsum[blockIdx.x];
}

// ---------------- CSR fill (no atomics: position precomputed) ----------------
__global__ __launch_bounds__(256) void fill_kernel(const int* __restrict__ ei, int E,
                                                   const int* __restrict__ rowstart,
                                                   const int* __restrict__ epos,
                                                   int* __restrict__ csr_col)
{
    const int e = blockIdx.x * 256 + threadIdx.x;
    if (e < E)
        csr_col[rowstart[ei[e]] + epos[e]] = ei[E + e];
}

// ---------------- fused attention: 4 edges/wave, 16 lanes/edge --------------
// lane: g=l>>4 edge slot, h=(l>>2)&3 head, dr=l&3 -> dims [dr*16, dr*16+16)
__global__ __launch_bounds__(256) void attn_kernel(
    const unsigned short* __restrict__ QL, const unsigned short* __restrict__ KH,
    const int* __restrict__ rowstart, const int* __restrict__ csr_col,
    float* __restrict__ out, int base, int N)
{
    const int n = base + blockIdx.x * 4 + (threadIdx.x >> 6);
    if (n >= N) return;
    const int l  = threadIdx.x & 63;
    const int g  = l >> 4;
    const int koff = ((l >> 2) & 3) * 64 + (l & 3) * 16;   // h*64 + dr*16 (shorts)

    // Q fragment: 16 dims of (h, dr)
    float qf[16];
    {
        const uint4* qp = (const uint4*)(QL + (size_t)n * FEAT + koff);
        const uint4 q0 = qp[0], q1 = qp[1];
        unsigned qs[8] = {q0.x, q0.y, q0.z, q0.w, q1.x, q1.y, q1.z, q1.w};
        #pragma unroll
        for (int tt = 0; tt < 8; ++tt) {
            qf[2 * tt]     = bflo(qs[tt]);
            qf[2 * tt + 1] = bfhi(qs[tt]);
        }
    }

    const int s0 = rowstart[n];
    const int s1 = rowstart[n + 1];

    float acc[16];
    #pragma unroll
    for (int j = 0; j < 16; ++j) acc[j] = 0.f;
    float z = 0.f;

    for (int i = s0; i < s1; i += 4) {
        const int eidx = i + g;
        if (eidx < s1) {
            const int c = csr_col[eidx];
            const uint4* kp = (const uint4*)(KH + (size_t)c * KHROW + koff);
            const uint4 k0 = kp[0],  k1 = kp[1];     // 32B of K
            const uint4 h0 = kp[32], h1 = kp[33];    // 32B of H (+256 shorts)

            unsigned ks[8] = {k0.x, k0.y, k0.z, k0.w, k1.x, k1.y, k1.z, k1.w};
            float p = 0.f;
            #pragma unroll
            for (int tt = 0; tt < 8; ++tt) {
                p = fmaf(qf[2 * tt],     bflo(ks[tt]), p);
                p = fmaf(qf[2 * tt + 1], bfhi(ks[tt]), p);
            }
            // reduce across the 4 dr lanes
            p += __shfl_xor(p, 1);
            p += __shfl_xor(p, 2);

            const float e = __expf(p * 0.125f);   // no-max softmax (shift-inv.)
            z += e;
            unsigned hs[8] = {h0.x, h0.y, h0.z, h0.w, h1.x, h1.y, h1.z, h1.w};
            #pragma unroll
            for (int tt = 0; tt < 8; ++tt) {
                acc[2 * tt]     = fmaf(e, bflo(hs[tt]), acc[2 * tt]);
                acc[2 * tt + 1] = fmaf(e, bfhi(hs[tt]), acc[2 * tt + 1]);
            }
        }
    }

    // sum across the 4 edge slots
    z += __shfl_xor(z, 16);
    z += __shfl_xor(z, 32);
    #pragma unroll
    for (int j = 0; j < 16; ++j) {
        acc[j] += __shfl_xor(acc[j], 16);
        acc[j] += __shfl_xor(acc[j], 32);
    }
    // normalize per head, then mean over heads
    const float inv = 0.25f / (z + 1e-8f);
    #pragma unroll
    for (int j = 0; j < 16; ++j) {
        float r = acc[j] * inv;
        r += __shfl_xor(r, 4);
        r += __shfl_xor(r, 8);
        acc[j] = r;
    }
    if (l < 4) {   // g=0,h=0, dr=l: dims [l*16, l*16+16)
        float* ob = out + (size_t)n * NOUT + l * 16;
        *(float4*)(ob + 0)  = make_float4(acc[0],  acc[1],  acc[2],  acc[3]);
        *(float4*)(ob + 4)  = make_float4(acc[4],  acc[5],  acc[6],  acc[7]);
        *(float4*)(ob + 8)  = make_float4(acc[8],  acc[9],  acc[10], acc[11]);
        *(float4*)(ob + 12) = make_float4(acc[12], acc[13], acc[14], acc[15]);
    }
}

// ---------------- launch ----------------
extern "C" void kernel_launch(void* const* d_in, const int* in_sizes, int n_in,
                              void* d_out, int out_size, void* d_ws, size_t ws_size,
                              hipStream_t stream)
{
    const float* x  = (const float*)d_in[0];
    const int*   ei = (const int*)d_in[1];
    const float* Wq = (const float*)d_in[2];
    const float* Wk = (const float*)d_in[3];
    const float* Wh = (const float*)d_in[4];
    const float* bh = (const float*)d_in[5];
    float* out = (float*)d_out;
    const int N = in_sizes[0] / NIN;   // 100000
    const int E = in_sizes[1] / 2;     // 1600000

    char* p = (char*)d_ws;
    auto alloc = [&](size_t bytes) {
        char* r = p;
        p += (bytes + 255) & ~(size_t)255;
        return r;
    };
    unsigned short* QL  = (unsigned short*)alloc((size_t)N * FEAT * 2);
    unsigned short* KH  = (unsigned short*)alloc((size_t)N * KHROW * 2);
    unsigned short* Wsw = (unsigned short*)alloc((size_t)12288 * 8 * 2);
    int* deg      = (int*)alloc((size_t)N * 4);
    int* rowstart = (int*)alloc((size_t)(N + 1) * 4);
    int* epos     = (int*)alloc((size_t)E * 4);
    int* csr_col  = (int*)alloc((size_t)(E + 8) * 4);
    int* bsum     = (int*)alloc((size_t)1024 * 4);

    const int NB = (N + 1023) / 1024;   // 98
    const int GB = (N + 127) / 128;     // 782 gemm blocks

    hipMemsetAsync(deg, 0, (size_t)N * 4, stream);

    wconv_kernel<<<48, 256, 0, stream>>>(Wq, Wk, Wh, Wsw);
    gemm_mfma_kernel<<<GB + 512, 256, 0, stream>>>(x, Wsw, bh, QL, KH, N,
                                                   ei, E, deg, epos, GB);
    bsum_kernel<<<NB, 1024, 0, stream>>>(deg, N, bsum);
    bscan_kernel<<<1, 1024, 0, stream>>>(bsum, NB, rowstart, N);
    scan_apply_kernel<<<NB, 1024, 0, stream>>>(deg, bsum, N, rowstart);
    fill_kernel<<<(E + 255) / 256, 256, 0, stream>>>(ei, E, rowstart, epos, csr_col);

    // attention split into two half-range dispatches (visibility + tail overlap)
    const int B1 = (N + 7) / 8;              // blocks covering first ~half
    const int Btot = (N + 3) / 4;
    const int B2 = Btot - B1;
    attn_kernel<<<B1, 256, 0, stream>>>(QL, KH, rowstart, csr_col, out, 0, N);
    attn_kernel<<<B2, 256, 0, stream>>>(QL, KH, rowstart, csr_col, out, B1 * 4, N);
}

// Round 10
// 347.132 us; speedup vs baseline: 1.5410x; 1.0308x over previous
//
#include <hip/hip_runtime.h>
#include <math.h>

#define NIN 128
#define NOUT 64
#define FEAT 256        // QL row: 256 bf16 = 512B
#define KHROW 512       // KH row: [K01 256B | H01 256B | K23 256B | H23 256B]

typedef __attribute__((ext_vector_type(8))) short short8;
typedef __attribute__((ext_vector_type(4))) float f32x4;

__device__ __forceinline__ unsigned short f2bf(float f) {
    unsigned u = __float_as_uint(f);
    u = (u + 0x7FFFu + ((u >> 16) & 1u)) >> 16;   // RTNE
    return (unsigned short)u;
}
__device__ __forceinline__ float bflo(unsigned u) {
    return __uint_as_float(u << 16);
}
__device__ __forceinline__ float bfhi(unsigned u) {
    return __uint_as_float(u & 0xffff0000u);
}

// ---------------- W fp32 -> bf16, pre-swizzled to MFMA A-fragment order ------
__global__ __launch_bounds__(256) void wconv_kernel(
    const float* __restrict__ Wq, const float* __restrict__ Wk,
    const float* __restrict__ Wh, unsigned short* __restrict__ Wsw)
{
    const int id = blockIdx.x * 256 + threadIdx.x;   // 12288 total
    const int lane = id & 63;
    const int kb   = (id >> 6) & 3;
    const int tile = (id >> 8) & 3;
    const int head = (id >> 10) & 3;
    const int mat  = id >> 12;
    const float* src = (mat == 0) ? Wq : (mat == 1) ? Wk : Wh;
    const int row   = tile * 16 + (lane & 15);
    const int kbase = kb * 32 + (lane >> 4) * 8;
    const float* sp = src + (size_t)(head * 64 + row) * NIN + kbase;
    const float4 a = *(const float4*)sp;
    const float4 b = *(const float4*)(sp + 4);
    uint4 w;
    w.x = (unsigned)f2bf(a.x) | ((unsigned)f2bf(a.y) << 16);
    w.y = (unsigned)f2bf(a.z) | ((unsigned)f2bf(a.w) << 16);
    w.z = (unsigned)f2bf(b.x) | ((unsigned)f2bf(b.y) << 16);
    w.w = (unsigned)f2bf(b.z) | ((unsigned)f2bf(b.w) << 16);
    *(uint4*)(Wsw + (size_t)id * 8) = w;
}

// ---------------- MFMA GEMM (BM=128, W staged via LDS) + fused degree/epos ---
__global__ __launch_bounds__(256) void gemm_mfma_kernel(
    const float* __restrict__ x, const unsigned short* __restrict__ Wsw,
    const float* __restrict__ bh,
    unsigned short* __restrict__ QL, unsigned short* __restrict__ KH, int N,
    const int* __restrict__ ei, int E, int* __restrict__ deg,
    int* __restrict__ epos, int GB)
{
    if (blockIdx.x >= GB) {   // ---- degree-count + edge-position side job ----
        for (int e = (blockIdx.x - GB) * 256 + threadIdx.x; e < E; e += 512 * 256)
            epos[e] = atomicAdd(&deg[ei[e]], 1);
        return;
    }

    __shared__ char smem[34816];   // xs staging; then bounce | W stage
    unsigned short (*xs)[136] = (unsigned short (*)[136])smem;

    const int nb = blockIdx.x * 128;
    const int t  = threadIdx.x;
    const int w  = t >> 6;
    const int l  = t & 63;

    #pragma unroll
    for (int j = 0; j < 16; ++j) {
        const int idx = j * 256 + t;
        const int row = idx >> 5;
        const int c4  = idx & 31;
        float4 xv = make_float4(0.f, 0.f, 0.f, 0.f);
        if (nb + row < N)
            xv = *(const float4*)(x + (size_t)(nb + row) * NIN + c4 * 4);
        ushort4 pk;
        pk.x = f2bf(xv.x); pk.y = f2bf(xv.y); pk.z = f2bf(xv.z); pk.w = f2bf(xv.w);
        *(ushort4*)(&xs[row][c4 * 4]) = pk;
    }
    __syncthreads();

    short8 bfrx[2][4];
    #pragma unroll
    for (int ns = 0; ns < 2; ++ns)
        #pragma unroll
        for (int kb = 0; kb < 4; ++kb)
            bfrx[ns][kb] = *(const short8*)(
                &xs[w * 32 + ns * 16 + (l & 15)][kb * 32 + (l >> 4) * 8]);
    __syncthreads();   // reuse smem as bounce + W stage

    char* const sbw = smem + w * 4608;                       // 32 nodes x 144B
    unsigned short* const wl = (unsigned short*)(smem + 18432);  // 16KB W stage
    const int fsub = (l >> 4) * 4;

    for (int g = 0; g < 12; ++g) {
        const int mat  = g >> 2;
        const int head = g & 3;

        {
            const uint4* gw = (const uint4*)(Wsw + (size_t)g * 8192);
            uint4* wl4 = (uint4*)wl;
            #pragma unroll
            for (int j = 0; j < 4; ++j)
                wl4[j * 256 + t] = gw[j * 256 + t];
        }
        __syncthreads();

        #pragma unroll
        for (int tile = 0; tile < 4; ++tile) {
            f32x4 a0 = (f32x4){0.f, 0.f, 0.f, 0.f};
            f32x4 a1 = (f32x4){0.f, 0.f, 0.f, 0.f};
            #pragma unroll
            for (int kb = 0; kb < 4; ++kb) {
                const short8 afrw = *(const short8*)(
                    wl + (((tile * 4 + kb) << 9) + (l << 3)));
                a0 = __builtin_amdgcn_mfma_f32_16x16x32_bf16(afrw, bfrx[0][kb], a0, 0, 0, 0);
                a1 = __builtin_amdgcn_mfma_f32_16x16x32_bf16(afrw, bfrx[1][kb], a1, 0, 0, 0);
            }
            #pragma unroll
            for (int ns = 0; ns < 2; ++ns) {
                const f32x4 av = ns ? a1 : a0;
                float v0 = av[0], v1 = av[1], v2 = av[2], v3 = av[3];
                const int node = (l & 15) + ns * 16;
                if (mat == 2) {
                    const float4 bv = *(const float4*)(bh + head * NOUT + tile * 16 + fsub);
                    v0 += bv.x; v1 += bv.y; v2 += bv.z; v3 += bv.w;
                } else {
                    v0 = (v0 > 0.f) ? v0 : 0.2f * v0;
                    v1 = (v1 > 0.f) ? v1 : 0.2f * v1;
                    v2 = (v2 > 0.f) ? v2 : 0.2f * v2;
                    v3 = (v3 > 0.f) ? v3 : 0.2f * v3;
                }
                uint2 pk;
                pk.x = (unsigned)f2bf(v0) | ((unsigned)f2bf(v1) << 16);
                pk.y = (unsigned)f2bf(v2) | ((unsigned)f2bf(v3) << 16);
                *(uint2*)(sbw + node * 144 + (tile * 16 + fsub) * 2) = pk;
            }
        }

        // store: 8 nodes per instruction, 1KB fully-contiguous per wave op
        #pragma unroll
        for (int jj = 0; jj < 4; ++jj) {
            const int node  = (l >> 3) + jj * 8;
            const int gnode = nb + w * 32 + node;
            const uint4 v = *(const uint4*)(sbw + node * 144 + (l & 7) * 16);
            if (gnode < N) {
                char* ob;
                if (mat == 0) {
                    ob = (char*)QL + (size_t)gnode * 512 + head * 128;
                } else {
                    // head-pair layout: [K01|H01|K23|H23], 128B per head-half
                    const int pb = (head >> 1) * 512 + (head & 1) * 128
                                 + (mat == 2 ? 256 : 0);
                    ob = (char*)KH + (size_t)gnode * 1024 + pb;
                }
                *(uint4*)(ob + (l & 7) * 16) = v;
            }
        }
        __syncthreads();
    }
}

// ---------------- multi-block scan ----------------
__global__ __launch_bounds__(1024) void bsum_kernel(const int* __restrict__ deg, int N,
                                                    int* __restrict__ bsum)
{
    __shared__ int wsum[16];
    const int t = threadIdx.x;
    const int idx = blockIdx.x * 1024 + t;
    int v = (idx < N) ? deg[idx] : 0;
    #pragma unroll
    for (int off = 1; off < 64; off <<= 1) v += __shfl_xor(v, off);
    if ((t & 63) == 0) wsum[t >> 6] = v;
    __syncthreads();
    if (t < 16) {
        int s = wsum[t];
        #pragma unroll
        for (int off = 1; off < 16; off <<= 1) s += __shfl_xor(s, off);
        if (t == 0) bsum[blockIdx.x] = s;
    }
}

__global__ __launch_bounds__(1024) void bscan_kernel(int* __restrict__ bsum, int NB,
                                                     int* __restrict__ rowstart, int N)
{
    __shared__ int wsum[16];
    const int t = threadIdx.x, lane = t & 63, wid = t >> 6;
    const int v = (t < NB) ? bsum[t] : 0;
    int s = v;
    #pragma unroll
    for (int off = 1; off < 64; off <<= 1) {
        int u = __shfl_up(s, off);
        if (lane >= off) s += u;
    }
    if (lane == 63) wsum[wid] = s;
    __syncthreads();
    if (wid == 0 && lane < 16) {
        int ss = wsum[lane];
        #pragma unroll
        for (int off = 1; off < 16; off <<= 1) {
            int u = __shfl_up(ss, off);
            if (lane >= off) ss += u;
        }
        wsum[lane] = ss;
    }
    __syncthreads();
    const int woff = (wid == 0) ? 0 : wsum[wid - 1];
    if (t < NB) bsum[t] = s + woff - v;
    if (t == 1023) rowstart[N] = s + woff;
}

__global__ __launch_bounds__(1024) void scan_apply_kernel(
    const int* __restrict__ deg, const int* __restrict__ bsum, int N,
    int* __restrict__ rowstart)
{
    __shared__ int wsum[16];
    const int t = threadIdx.x, lane = t & 63, wid = t >> 6;
    const int idx = blockIdx.x * 1024 + t;
    const int v = (idx < N) ? deg[idx] : 0;
    int s = v;
    #pragma unroll
    for (int off = 1; off < 64; off <<= 1) {
        int u = __shfl_up(s, off);
        if (lane >= off) s += u;
    }
    if (lane == 63) wsum[wid] = s;
    __syncthreads();
    if (wid == 0 && lane < 16) {
        int ss = wsum[lane];
        #pragma unroll
        for (int off = 1; off < 16; off <<= 1) {
            int u = __shfl_up(ss, off);
            if (lane >= off) ss += u;
        }
        wsum[lane] = ss;
    }
    __syncthreads();
    const int woff = (wid == 0) ? 0 : wsum[wid - 1];
    if (idx < N) rowstart[idx] = s + woff - v + bsum[blockIdx.x];
}

// ---------------- CSR fill (no atomics: position precomputed) ----------------
__global__ __launch_bounds__(256) void fill_kernel(const int* __restrict__ ei, int E,
                                                   const int* __restrict__ rowstart,
                                                   const int* __restrict__ epos,
                                                   int* __restrict__ csr_col)
{
    const int e = blockIdx.x * 256 + threadIdx.x;
    if (e < E)
        csr_col[rowstart[ei[e]] + epos[e]] = ei[E + e];
}

// ---------------- fused attention, head-pair pass hp (0: heads 0-1, 1: 2-3) --
// lane: g=l>>4 edge slot, h2=(l>>3)&1 head-in-pair, dr=l&7 -> dims [dr*8,dr*8+8)
// Per edge: 16 lanes read 256B K + 256B H (one head-pair only).
__global__ __launch_bounds__(256) void attn_kernel(
    const unsigned short* __restrict__ QL, const unsigned short* __restrict__ KH,
    const int* __restrict__ rowstart, const int* __restrict__ csr_col,
    float* __restrict__ out, int N, int hp)
{
    const int n = blockIdx.x * 4 + (threadIdx.x >> 6);
    if (n >= N) return;
    const int l  = threadIdx.x & 63;
    const int g  = l >> 4;
    const int h2 = (l >> 3) & 1;
    const int dr = l & 7;
    const int kboff = hp * 512 + h2 * 128 + dr * 16;        // K byte offset in row
    const int hboff = kboff + 256;                           // H byte offset

    // Q fragment: 8 dims of head (hp*2+h2)
    float qf[8];
    {
        const uint4 qv = *(const uint4*)(QL + (size_t)n * FEAT
                                         + (hp * 2 + h2) * 64 + dr * 8);
        unsigned qs[4] = {qv.x, qv.y, qv.z, qv.w};
        #pragma unroll
        for (int tt = 0; tt < 4; ++tt) {
            qf[2 * tt]     = bflo(qs[tt]);
            qf[2 * tt + 1] = bfhi(qs[tt]);
        }
    }

    const int s0 = rowstart[n];
    const int s1 = rowstart[n + 1];

    float acc[8];
    #pragma unroll
    for (int j = 0; j < 8; ++j) acc[j] = 0.f;
    float z = 0.f;

    for (int i = s0; i < s1; i += 4) {
        const int eidx = i + g;
        if (eidx < s1) {
            const int c = csr_col[eidx];
            const char* base = (const char*)KH + (size_t)c * 1024;
            const uint4 ku = *(const uint4*)(base + kboff);   // 16B K (8 dims)
            const uint4 hu = *(const uint4*)(base + hboff);   // 16B H (8 dims)

            unsigned ks[4] = {ku.x, ku.y, ku.z, ku.w};
            float p = 0.f;
            #pragma unroll
            for (int tt = 0; tt < 4; ++tt) {
                p = fmaf(qf[2 * tt],     bflo(ks[tt]), p);
                p = fmaf(qf[2 * tt + 1], bfhi(ks[tt]), p);
            }
            // reduce across the 8 dr lanes (bits 0-2)
            p += __shfl_xor(p, 1);
            p += __shfl_xor(p, 2);
            p += __shfl_xor(p, 4);

            const float e = __expf(p * 0.125f);   // no-max softmax (shift-inv.)
            z += e;
            unsigned hs[4] = {hu.x, hu.y, hu.z, hu.w};
            #pragma unroll
            for (int tt = 0; tt < 4; ++tt) {
                acc[2 * tt]     = fmaf(e, bflo(hs[tt]), acc[2 * tt]);
                acc[2 * tt + 1] = fmaf(e, bfhi(hs[tt]), acc[2 * tt + 1]);
            }
        }
    }

    // sum across the 4 edge slots (bits 4,5)
    z += __shfl_xor(z, 16);
    z += __shfl_xor(z, 32);
    #pragma unroll
    for (int j = 0; j < 8; ++j) {
        acc[j] += __shfl_xor(acc[j], 16);
        acc[j] += __shfl_xor(acc[j], 32);
    }
    // normalize per head, then sum the head pair (bit 3)
    const float inv = 1.f / (z + 1e-8f);
    #pragma unroll
    for (int j = 0; j < 8; ++j) {
        float r = acc[j] * inv;
        r += __shfl_xor(r, 8);
        acc[j] = r;
    }
    if (l < 8) {   // g=0,h2=0, dr=l: dims [l*8, l*8+8)
        float* ob = out + (size_t)n * NOUT + l * 8;
        if (hp == 0) {   // pass A: write head-pair partial sum
            *(float4*)(ob + 0) = make_float4(acc[0], acc[1], acc[2], acc[3]);
            *(float4*)(ob + 4) = make_float4(acc[4], acc[5], acc[6], acc[7]);
        } else {         // pass B: add + final mean over 4 heads
            const float4 p0 = *(const float4*)(ob + 0);
            const float4 p1 = *(const float4*)(ob + 4);
            *(float4*)(ob + 0) = make_float4((p0.x + acc[0]) * 0.25f,
                                             (p0.y + acc[1]) * 0.25f,
                                             (p0.z + acc[2]) * 0.25f,
                                             (p0.w + acc[3]) * 0.25f);
            *(float4*)(ob + 4) = make_float4((p1.x + acc[4]) * 0.25f,
                                             (p1.y + acc[5]) * 0.25f,
                                             (p1.z + acc[6]) * 0.25f,
                                             (p1.w + acc[7]) * 0.25f);
        }
    }
}

// ---------------- launch ----------------
extern "C" void kernel_launch(void* const* d_in, const int* in_sizes, int n_in,
                              void* d_out, int out_size, void* d_ws, size_t ws_size,
                              hipStream_t stream)
{
    const float* x  = (const float*)d_in[0];
    const int*   ei = (const int*)d_in[1];
    const float* Wq = (const float*)d_in[2];
    const float* Wk = (const float*)d_in[3];
    const float* Wh = (const float*)d_in[4];
    const float* bh = (const float*)d_in[5];
    float* out = (float*)d_out;
    const int N = in_sizes[0] / NIN;   // 100000
    const int E = in_sizes[1] / 2;     // 1600000

    char* p = (char*)d_ws;
    auto alloc = [&](size_t bytes) {
        char* r = p;
        p += (bytes + 255) & ~(size_t)255;
        return r;
    };
    unsigned short* QL  = (unsigned short*)alloc((size_t)N * FEAT * 2);
    unsigned short* KH  = (unsigned short*)alloc((size_t)N * KHROW * 2);
    unsigned short* Wsw = (unsigned short*)alloc((size_t)12288 * 8 * 2);
    int* deg      = (int*)alloc((size_t)N * 4);
    int* rowstart = (int*)alloc((size_t)(N + 1) * 4);
    int* epos     = (int*)alloc((size_t)E * 4);
    int* csr_col  = (int*)alloc((size_t)(E + 8) * 4);
    int* bsum     = (int*)alloc((size_t)1024 * 4);

    const int NB = (N + 1023) / 1024;   // 98
    const int GB = (N + 127) / 128;     // 782 gemm blocks

    hipMemsetAsync(deg, 0, (size_t)N * 4, stream);

    wconv_kernel<<<48, 256, 0, stream>>>(Wq, Wk, Wh, Wsw);
    gemm_mfma_kernel<<<GB + 512, 256, 0, stream>>>(x, Wsw, bh, QL, KH, N,
                                                   ei, E, deg, epos, GB);
    bsum_kernel<<<NB, 1024, 0, stream>>>(deg, N, bsum);
    bscan_kernel<<<1, 1024, 0, stream>>>(bsum, NB, rowstart, N);
    scan_apply_kernel<<<NB, 1024, 0, stream>>>(deg, bsum, N, rowstart);
    fill_kernel<<<(E + 255) / 256, 256, 0, stream>>>(ei, E, rowstart, epos, csr_col);

    // attention: two head-pair passes (working set halved per pass)
    const int AB = (N + 3) / 4;
    attn_kernel<<<AB, 256, 0, stream>>>(QL, KH, rowstart, csr_col, out, N, 0);
    attn_kernel<<<AB, 256, 0, stream>>>(QL, KH, rowstart, csr_col, out, N, 1);
}